// Round 9
// baseline (87.408 us; speedup 1.0000x reference)
//
#include <hip/hip_runtime.h>
#include <hip/hip_bf16.h>

// Problem constants (AttentionalPlanarRemapping): N=32, C=64, H=W=128, E=512
#define NB   32
#define CC   64
#define HW   16384          // 128*128
#define EE   512
#define CC2  4096           // C*C
#define SROW 520            // padded LDS row stride (u16) to de-alias lh halves

using short8  = __attribute__((ext_vector_type(8))) short;
using f32x16  = __attribute__((ext_vector_type(16))) float;
using f32x4   = __attribute__((ext_vector_type(4))) float;

// fp32 -> bf16 with round-to-nearest-even (bit twiddle, no API dependence)
__device__ __forceinline__ unsigned short f2bf(float x) {
    unsigned int u = __float_as_uint(x);
    u += 0x7FFFu + ((u >> 16) & 1u);
    return (unsigned short)(u >> 16);
}

// ---------------------------------------------------------------------------
// Kernel 1: logits[n][j] = dot(atts[n,:], W[j,:]) + b[j]   (unchanged R7)
// ---------------------------------------------------------------------------
__global__ __launch_bounds__(256) void logits_kernel(
    const float* __restrict__ atts, const float* __restrict__ W,
    const float* __restrict__ b, float* __restrict__ logits) {
    const int t  = threadIdx.x;
    const int j  = blockIdx.x * 2 + (t & 1);
    const int n  = (t >> 1) & 31;
    const int kq = t >> 6;                 // 0..3
    const float* __restrict__ wrow = W + (size_t)j * EE + kq * 128;
    const float* __restrict__ arow = atts + (size_t)n * EE + kq * 128;
    float acc0 = 0.f, acc1 = 0.f;
    #pragma unroll
    for (int k = 0; k < 128; k += 8) {
        float4 w0 = *reinterpret_cast<const float4*>(wrow + k);
        float4 a0 = *reinterpret_cast<const float4*>(arow + k);
        float4 w1 = *reinterpret_cast<const float4*>(wrow + k + 4);
        float4 a1 = *reinterpret_cast<const float4*>(arow + k + 4);
        acc0 = fmaf(w0.x, a0.x, acc0); acc0 = fmaf(w0.y, a0.y, acc0);
        acc0 = fmaf(w0.z, a0.z, acc0); acc0 = fmaf(w0.w, a0.w, acc0);
        acc1 = fmaf(w1.x, a1.x, acc1); acc1 = fmaf(w1.y, a1.y, acc1);
        acc1 = fmaf(w1.z, a1.z, acc1); acc1 = fmaf(w1.w, a1.w, acc1);
    }
    __shared__ float part[256];
    part[t] = acc0 + acc1;           // index = kq*64 + n*2 + j  (== t)
    __syncthreads();
    if (t < 64) {
        const int jj = blockIdx.x * 2 + (t & 1);
        const int nn = t >> 1;
        const float r = part[t] + part[t + 64] + part[t + 128] + part[t + 192];
        logits[(size_t)nn * CC2 + jj] = r + b[jj];
    }
}

// ---------------------------------------------------------------------------
// Kernel 2: double softmax, packed A output (unchanged R7):
//   a_pk[n][ks][half][l][e] = a[n][c=32*half+(l&31)][k=ks*16+(l>>5)*8+e]
// ---------------------------------------------------------------------------
__global__ __launch_bounds__(256) void softmax_kernel(
    const float* __restrict__ logits, unsigned short* __restrict__ a_pk) {
    const int n = blockIdx.x;
    const int t = threadIdx.x;
    __shared__ float s[CC2];
    __shared__ float wmax[4];
    __shared__ float wsum[4];

    const float* __restrict__ L = logits + (size_t)n * CC2;

    float lmax = -1e30f;
    for (int i = t; i < CC2; i += 256) {
        float v = L[i];
        s[i] = v;
        lmax = fmaxf(lmax, v);
    }
    #pragma unroll
    for (int off = 32; off > 0; off >>= 1) lmax = fmaxf(lmax, __shfl_xor(lmax, off));
    if ((t & 63) == 0) wmax[t >> 6] = lmax;
    __syncthreads();
    const float bmax = fmaxf(fmaxf(wmax[0], wmax[1]), fmaxf(wmax[2], wmax[3]));

    float lsum = 0.f;
    for (int i = t; i < CC2; i += 256) {
        float e = __expf(s[i] - bmax);
        s[i] = e;
        lsum += e;
    }
    #pragma unroll
    for (int off = 32; off > 0; off >>= 1) lsum += __shfl_xor(lsum, off);
    if ((t & 63) == 0) wsum[t >> 6] = lsum;
    __syncthreads();
    const float inv = 1.f / (wsum[0] + wsum[1] + wsum[2] + wsum[3]);

    for (int i = t; i < CC2; i += 256) s[i] *= inv;
    __syncthreads();

    const int c = t >> 2;          // 0..63
    const int q = t & 3;           // ks = 0..3
    const float* __restrict__ row = s + c * CC + q * 16;
    float mx = -1e30f;
    #pragma unroll
    for (int i = 0; i < 16; ++i) mx = fmaxf(mx, row[i]);
    mx = fmaxf(mx, __shfl_xor(mx, 1));
    mx = fmaxf(mx, __shfl_xor(mx, 2));
    float sum = 0.f;
    #pragma unroll
    for (int i = 0; i < 16; ++i) sum += __expf(row[i] - mx);
    sum += __shfl_xor(sum, 1);
    sum += __shfl_xor(sum, 2);
    const float isum = 1.f / sum;

    union { uint4 u[2]; unsigned short h[16]; } pk;
    #pragma unroll
    for (int i = 0; i < 16; ++i) pk.h[i] = f2bf(__expf(row[i] - mx) * isum);

    const int half = c >> 5;
    const int lc2  = c & 31;
    unsigned short* __restrict__ base =
        a_pk + (size_t)n * CC2 + (size_t)(q * 2 + half) * 512;
    *reinterpret_cast<uint4*>(base + lc2 * 8)        = pk.u[0];
    *reinterpret_cast<uint4*>(base + (32 + lc2) * 8) = pk.u[1];
}

// ---------------------------------------------------------------------------
// Kernel 3 (MFMA, double-buffered k-halves, LDS-gathered stores):
//   out[n,c,px] = sum_d a[n,c,d] * img[n,d,px]
// grid (32 px-tiles, 32 n) x 512 thr (8 waves). Tile = [64 d][512 px].
// Pipeline: stage d0..31 -> bar -> issue d32..63 loads ; compute half0 ;
//           write half1 LDS -> bar -> compute half1 -> bar -> epilogue.
// Epilogue: accs -> LDS f32 tile [32][512] (2 c-half passes), then contiguous
//           1-KB-per-instr nontemporal float4 stores.
// Wave wv owns px cols wv*64..wv*64+63 (2 MFMA col-tiles); A-frags hoisted.
// ---------------------------------------------------------------------------
template<int BUF, int H>
__device__ __forceinline__ void compute_half(
    const unsigned short* sImg, const short8* afrag, int lh, int pxw0, int pxw1,
    f32x16& acc00, f32x16& acc01, f32x16& acc10, f32x16& acc11) {
    #pragma unroll
    for (int ksl = 0; ksl < 2; ++ksl) {
        const unsigned short* sb = sImg + BUF * 32 * SROW + (ksl * 16) * SROW + lh * 8 * SROW;
        union { short8 v; unsigned short sh[8]; } b0, b1;
        #pragma unroll
        for (int e = 0; e < 8; ++e) {
            b0.sh[e] = sb[e * SROW + pxw0];
            b1.sh[e] = sb[e * SROW + pxw1];
        }
        acc00 = __builtin_amdgcn_mfma_f32_32x32x16_bf16(afrag[(H*2+ksl)*2+0], b0.v, acc00, 0, 0, 0);
        acc10 = __builtin_amdgcn_mfma_f32_32x32x16_bf16(afrag[(H*2+ksl)*2+1], b0.v, acc10, 0, 0, 0);
        acc01 = __builtin_amdgcn_mfma_f32_32x32x16_bf16(afrag[(H*2+ksl)*2+0], b1.v, acc01, 0, 0, 0);
        acc11 = __builtin_amdgcn_mfma_f32_32x32x16_bf16(afrag[(H*2+ksl)*2+1], b1.v, acc11, 0, 0, 0);
    }
}

__global__ __launch_bounds__(512, 4) void einsum_kernel(
    const float* __restrict__ img, const unsigned short* __restrict__ a_pk,
    float* __restrict__ out) {
    const int t    = threadIdx.x;
    const int lane = t & 63;
    const int wv   = t >> 6;                   // wave 0..7
    const int n    = blockIdx.y;
    const int px0  = blockIdx.x * 512;
    const int lh   = lane >> 5;
    const int lc   = lane & 31;

    __shared__ __align__(16) unsigned short sImg[2 * 32 * SROW];  // 66560 B (>= 64 KB f32 out tile)

    const float* __restrict__ gbase = img + (size_t)n * (CC * HW) + px0;
    const int px_l = (t & 127) * 4;            // 0..508
    const int dgrp = t >> 7;                   // 0..3 -> rows dgrp*8+j

    // ---- hoist all 8 A-fragment loads (L2-hot, 1 KB/wave each) ----
    const unsigned short* __restrict__ apn = a_pk + (size_t)n * CC2;
    short8 afrag[8];
    #pragma unroll
    for (int i = 0; i < 8; ++i)
        afrag[i] = *reinterpret_cast<const short8*>(apn + i * 512 + lane * 8);

    // ---- stage k-half 0 (d = 0..31) into buf0 ----
    {
        float4 v[8];
        #pragma unroll
        for (int j = 0; j < 8; ++j)
            v[j] = *reinterpret_cast<const float4*>(gbase + (size_t)(dgrp * 8 + j) * HW + px_l);
        #pragma unroll
        for (int j = 0; j < 8; ++j) {
            union { uint2 u; unsigned short h4[4]; } pk;
            pk.h4[0] = f2bf(v[j].x); pk.h4[1] = f2bf(v[j].y);
            pk.h4[2] = f2bf(v[j].z); pk.h4[3] = f2bf(v[j].w);
            *reinterpret_cast<uint2*>(&sImg[(dgrp * 8 + j) * SROW + px_l]) = pk.u;
        }
    }
    __syncthreads();

    f32x16 acc00 = {}, acc01 = {}, acc10 = {}, acc11 = {};
    const int pxw0 = wv * 64 + lc;
    const int pxw1 = pxw0 + 32;

    // ---- issue k-half 1 loads (d = 32..63); latency hides under compute 0 ----
    float4 v1[8];
    #pragma unroll
    for (int j = 0; j < 8; ++j)
        v1[j] = *reinterpret_cast<const float4*>(gbase + (size_t)(32 + dgrp * 8 + j) * HW + px_l);

    compute_half<0, 0>(sImg, afrag, lh, pxw0, pxw1, acc00, acc01, acc10, acc11);

    // ---- write k-half 1 into buf1 ----
    #pragma unroll
    for (int j = 0; j < 8; ++j) {
        union { uint2 u; unsigned short h4[4]; } pk;
        pk.h4[0] = f2bf(v1[j].x); pk.h4[1] = f2bf(v1[j].y);
        pk.h4[2] = f2bf(v1[j].z); pk.h4[3] = f2bf(v1[j].w);
        *reinterpret_cast<uint2*>(&sImg[32 * SROW + (dgrp * 8 + j) * SROW + px_l]) = pk.u;
    }
    __syncthreads();

    compute_half<1, 1>(sImg, afrag, lh, pxw0, pxw1, acc00, acc01, acc10, acc11);
    __syncthreads();   // all LDS reads done; safe to reuse as f32 out tile

    // ---- epilogue: 2 passes of [32 c][512 px] f32 via LDS, contiguous stores
    float* sOut = reinterpret_cast<float*>(sImg);
    float* __restrict__ obase = out + (size_t)n * (CC * HW) + px0;

    // pass A: c = 0..31
    #pragma unroll
    for (int r = 0; r < 16; ++r) {
        const int row = (r & 3) + 8 * (r >> 2) + 4 * lh;
        sOut[row * 512 + pxw0] = acc00[r];
        sOut[row * 512 + pxw1] = acc01[r];
    }
    __syncthreads();
    #pragma unroll
    for (int k = 0; k < 8; ++k) {
        const int f4  = t + k * 512;         // 0..4095
        const int row = f4 >> 7;             // 0..31
        const int px4 = f4 & 127;
        const f32x4 val = reinterpret_cast<const f32x4*>(sOut)[f4];
        __builtin_nontemporal_store(val,
            reinterpret_cast<f32x4*>(obase + (size_t)row * HW + px4 * 4));
    }
    __syncthreads();

    // pass B: c = 32..63
    #pragma unroll
    for (int r = 0; r < 16; ++r) {
        const int row = (r & 3) + 8 * (r >> 2) + 4 * lh;
        sOut[row * 512 + pxw0] = acc10[r];
        sOut[row * 512 + pxw1] = acc11[r];
    }
    __syncthreads();
    #pragma unroll
    for (int k = 0; k < 8; ++k) {
        const int f4  = t + k * 512;
        const int row = f4 >> 7;
        const int px4 = f4 & 127;
        const f32x4 val = reinterpret_cast<const f32x4*>(sOut)[f4];
        __builtin_nontemporal_store(val,
            reinterpret_cast<f32x4*>(obase + (size_t)(row + 32) * HW + px4 * 4));
    }
}

// ---------------------------------------------------------------------------
extern "C" void kernel_launch(void* const* d_in, const int* in_sizes, int n_in,
                              void* d_out, int out_size, void* d_ws, size_t ws_size,
                              hipStream_t stream) {
    const float* images = (const float*)d_in[0];   // [32,64,128,128]
    const float* atts   = (const float*)d_in[1];   // [32,512]
    const float* W      = (const float*)d_in[2];   // [4096,512]
    const float* b      = (const float*)d_in[3];   // [4096]
    float* out = (float*)d_out;                    // [32,64,128,128]

    // workspace: logits f32 [32*4096] (512 KB) then a_pk bf16 [32*4096] (256 KB)
    float* logits = (float*)d_ws;
    unsigned short* a_pk = (unsigned short*)(logits + NB * CC2);

    logits_kernel<<<CC2 / 2, 256, 0, stream>>>(atts, W, b, logits);
    softmax_kernel<<<NB, 256, 0, stream>>>(logits, a_pk);
    einsum_kernel<<<dim3(HW / 512, NB), 512, 0, stream>>>(images, a_pk, out);
}